// Round 5
// baseline (361.196 us; speedup 1.0000x reference)
//
#include <hip/hip_runtime.h>

#define NB 8
#define CC 256
#define TT 256
#define VV 25

typedef unsigned int u32;
typedef unsigned short u16;
typedef __attribute__((ext_vector_type(8))) short s16x8;
typedef __attribute__((ext_vector_type(4))) float f32x4;

__device__ __forceinline__ float bf2f(u16 u) { return __uint_as_float((u32)u << 16); }
__device__ __forceinline__ u16 f2bf(float f) {
    u32 u = __float_as_uint(f);
    u += 0x7fffu + ((u >> 16) & 1u);
    return (u16)(u >> 16);
}
// truncating bf16 (1 ulp; compiles to lshr or d16_hi store)
__device__ __forceinline__ u16 f2bf_rtz(float f) { return (u16)(__float_as_uint(f) >> 16); }

__device__ __forceinline__ void gload_lds16(const void* g, void* l) {
    __builtin_amdgcn_global_load_lds(
        (const __attribute__((address_space(1))) u32*)g,
        (__attribute__((address_space(3))) u32*)l, 16, 0, 0);
}

// ---------------------------------------------------------------------------
// K1: x (N,C,T,V) f32 -> xT[b=(n*V+v)][t][c] bf16  (k-contiguous rows for MFMA A/B)
__global__ __launch_bounds__(256) void k_transpose_x(const float* __restrict__ x,
                                                     u16* __restrict__ xT) {
    __shared__ u16 L[25 * 32 * 34];
    const int tid = threadIdx.x;
    const int c0 = blockIdx.x * 32;
    const int t0 = blockIdx.y * 32;
    const int n  = blockIdx.z;
    for (int i = tid; i < 25600; i += 256) {
        int ci = i / 800;
        int rem = i - ci * 800;
        int t = rem / 25;
        int v = rem - t * 25;
        float f = x[(((size_t)(n * CC + c0 + ci)) * TT + t0) * VV + rem];
        L[(v * 32 + t) * 34 + ci] = f2bf(f);
    }
    __syncthreads();
    for (int i = tid; i < 12800; i += 256) {
        int row = i >> 4, cp = i & 15;
        int v = row >> 5, t = row & 31;
        u32 val = *(const u32*)&L[row * 34 + cp * 2];
        *(u32*)&xT[(((size_t)(n * VV + v)) * TT + t0 + t) * CC + c0 + cp * 2] = val;
    }
}

// ---------------------------------------------------------------------------
// K1b: pack weights (q rows pre-scaled), scaled q bias, krel (512 rows, last zeroed)
__global__ __launch_bounds__(256) void k_pack_all(const float* __restrict__ qkv_w,
                                                  const float* __restrict__ attn_w,
                                                  const float* __restrict__ qkv_b,
                                                  const float* __restrict__ key_rel,
                                                  u16* __restrict__ Wqk,
                                                  u16* __restrict__ Wv,
                                                  u16* __restrict__ Wo,
                                                  float* __restrict__ bqk,
                                                  u16* __restrict__ krb) {
    const float s = 0.17677669529663687f;   // 1/sqrt(32)
    int g = blockIdx.x * 256 + threadIdx.x;
    if (g < 131072) {
        Wqk[g] = f2bf(qkv_w[g] * (g < 65536 ? s : 1.f));
    } else if (g < 196608) {
        Wv[g - 131072] = f2bf(qkv_w[g]);             // qkv_w rows 512..767
    } else if (g < 262144) {
        Wo[g - 196608] = f2bf(attn_w[g - 196608]);
    } else if (g < 262656) {
        int i = g - 262144;
        bqk[i] = qkv_b[i] * (i < 256 ? s : 1.f);
    } else if (g < 279040) {
        int i = g - 262656;
        krb[i] = (i < 511 * 32) ? f2bf(key_rel[i]) : (u16)0;
    }
}

// ---------------------------------------------------------------------------
// m97-style mainloop: 128x128 tile, BK=32, async global->LDS, 4 waves x (4x4) 16x16 tiles.
__device__ __forceinline__ void gemm_mainloop(const u16* __restrict__ Arow,
                                              const u16* __restrict__ Brow,
                                              u16* At, u16* Bt,
                                              int wave, int lane, f32x4 acc[4][4]) {
    const int srow = lane >> 2, scol = (lane & 3) * 8;
    const int quad = lane >> 4, l15 = lane & 15;
    for (int k0 = 0; k0 < 256; k0 += 32) {
#pragma unroll
        for (int it = 0; it < 2; ++it) {
            int ch = it * 4 + wave;
            gload_lds16(Arow + (size_t)(ch * 16 + srow) * 256 + k0 + scol, At + ch * 512 + lane * 8);
            gload_lds16(Brow + (size_t)(ch * 16 + srow) * 256 + k0 + scol, Bt + ch * 512 + lane * 8);
        }
        __syncthreads();
        s16x8 af[4], bfr[4];
#pragma unroll
        for (int i = 0; i < 4; ++i)
            af[i] = *(const s16x8*)&At[((wave & 1) * 64 + i * 16 + l15) * 32 + quad * 8];
#pragma unroll
        for (int j = 0; j < 4; ++j)
            bfr[j] = *(const s16x8*)&Bt[((wave >> 1) * 64 + j * 16 + l15) * 32 + quad * 8];
#pragma unroll
        for (int i = 0; i < 4; ++i)
#pragma unroll
            for (int j = 0; j < 4; ++j)
                acc[i][j] = __builtin_amdgcn_mfma_f32_16x16x32_bf16(af[i], bfr[j], acc[i][j], 0, 0, 0);
        __syncthreads();
    }
}

// ---------------------------------------------------------------------------
// K2a: C[t][o] = xT . Wqk^T + bqk  -> qk_all[b][t][512]  (cols 0..255 q, 256..511 k)
__global__ __launch_bounds__(256) void k_gemm_qk(const u16* __restrict__ xT,
                                                 const u16* __restrict__ Wqk,
                                                 const float* __restrict__ bqk,
                                                 u16* __restrict__ qk_all) {
    __shared__ __align__(16) u16 At[128 * 32];
    __shared__ __align__(16) u16 Bt[128 * 32];
    const int tid = threadIdx.x, wave = tid >> 6, lane = tid & 63;
    const int quad = lane >> 4, l15 = lane & 15;
    const int n0 = blockIdx.x * 128;     // o
    const int m0 = blockIdx.y * 128;     // t
    const int b  = blockIdx.z;
    const u16* Arow = xT + (size_t)b * 65536 + (size_t)m0 * 256;
    const u16* Brow = Wqk + (size_t)n0 * 256;
    f32x4 acc[4][4];
#pragma unroll
    for (int i = 0; i < 4; ++i)
#pragma unroll
        for (int j = 0; j < 4; ++j) acc[i][j] = (f32x4){0.f, 0.f, 0.f, 0.f};
    gemm_mainloop(Arow, Brow, At, Bt, wave, lane, acc);

    u16* ob = qk_all + (size_t)b * 131072;
    const int nb = n0 + (wave >> 1) * 64 + l15;
    float bj[4];
#pragma unroll
    for (int j = 0; j < 4; ++j) bj[j] = bqk[nb + j * 16];
#pragma unroll
    for (int i = 0; i < 4; ++i) {
        int t_i = m0 + (wave & 1) * 64 + i * 16 + quad * 4;
#pragma unroll
        for (int r = 0; r < 4; ++r) {
            u16* orow = ob + (size_t)(t_i + r) * 512 + nb;
#pragma unroll
            for (int j = 0; j < 4; ++j)
                orow[j * 16] = f2bf(acc[i][j][r] + bj[j]);
        }
    }
}

// ---------------------------------------------------------------------------
// K2b (used twice): C[o][t] = W . Bsrc^T + bias -> Out[b][o][t]
__global__ __launch_bounds__(256) void k_gemm_av(const u16* __restrict__ Wb,
                                                 const float* __restrict__ bias,
                                                 const u16* __restrict__ Bsrc,
                                                 u16* __restrict__ Out) {
    __shared__ __align__(16) u16 At[128 * 32];
    __shared__ __align__(16) u16 Bt[128 * 32];
    const int tid = threadIdx.x, wave = tid >> 6, lane = tid & 63;
    const int quad = lane >> 4, l15 = lane & 15;
    const int n0 = blockIdx.x * 128;     // t
    const int m0 = blockIdx.y * 128;     // o
    const int b  = blockIdx.z;
    const u16* Arow = Wb + (size_t)m0 * 256;
    const u16* Brow = Bsrc + (size_t)b * 65536 + (size_t)n0 * 256;
    f32x4 acc[4][4];
#pragma unroll
    for (int i = 0; i < 4; ++i)
#pragma unroll
        for (int j = 0; j < 4; ++j) acc[i][j] = (f32x4){0.f, 0.f, 0.f, 0.f};
    gemm_mainloop(Arow, Brow, At, Bt, wave, lane, acc);

    u16* ob = Out + (size_t)b * 65536;
    const int nb = n0 + (wave >> 1) * 64 + l15;
#pragma unroll
    for (int i = 0; i < 4; ++i) {
        int o_i = m0 + (wave & 1) * 64 + i * 16 + quad * 4;
#pragma unroll
        for (int r = 0; r < 4; ++r) {
            float bv = bias[o_i + r];
            u16* orow = ob + (size_t)(o_i + r) * 256 + nb;
#pragma unroll
            for (int j = 0; j < 4; ++j)
                orow[j * 16] = f2bf(acc[i][j][r] + bv);
        }
    }
}

// ---------------------------------------------------------------------------
// K3: wave-autonomous MFMA attention. Each wave owns 16 t-rows end-to-end.
//   p1: R band = Q·KR^T, truncating bf16 stores to wave-private LDS
//   p2: acc init = gathered R (LDS pipe), then acc += Q·K^T (VMEM+MFMA overlap),
//       wave-local tree softmax; truncating P stores
//   p3: O = P·V^T -> attnT[b][t][256]
// Zero __syncthreads. Stride 280 u16 keeps all LDS patterns <=2-way on banks.
__global__ __launch_bounds__(256, 4) void k_attention_mfma(const u16* __restrict__ qk,
                                                           const u16* __restrict__ vb,
                                                           const u16* __restrict__ krb,
                                                           u16* __restrict__ attn) {
    __shared__ __align__(16) u16 RP[4][16 * 280];

    const int tid = threadIdx.x;
    const int bh = blockIdx.x;
    const int b = bh >> 3, h = bh & 7;
    const int wave = tid >> 6, lane = tid & 63;
    const int quad = lane >> 4, l15 = lane & 15;
    const int t0w = blockIdx.y * 64 + wave * 16;    // this wave's first t-row
    const int tl = quad * 4;                        // C-layout row base (t-local)

    u16* rp = &RP[wave][0];
    const u16* qrow = qk + (size_t)b * 131072;             // [t][512]
    const u16* vg   = vb + (size_t)bh * 8192;              // [d][t]
    const u16* krg  = krb + (size_t)(240 - t0w) * 32;      // m = col + 240 - t0w

    // A fragment: Q rows t0w..t0w+15
    s16x8 afrag = *(const s16x8*)(qrow + (size_t)(t0w + l15) * 512 + h * 32 + quad * 8);

    // ---- phase 1: R band (cols 0..271)
#pragma unroll
    for (int j = 0; j < 17; ++j) {
        s16x8 bfrag = *(const s16x8*)(krg + (size_t)(j * 16 + l15) * 32 + quad * 8);
        f32x4 c = {0.f, 0.f, 0.f, 0.f};
        c = __builtin_amdgcn_mfma_f32_16x16x32_bf16(afrag, bfrag, c, 0, 0, 0);
        int col = j * 16 + l15;
        rp[(tl + 0) * 280 + col] = f2bf_rtz(c[0]);
        rp[(tl + 1) * 280 + col] = f2bf_rtz(c[1]);
        rp[(tl + 2) * 280 + col] = f2bf_rtz(c[2]);
        rp[(tl + 3) * 280 + col] = f2bf_rtz(c[3]);
    }

    // ---- phase 2: acc init from R gather, then S += Q K^T
    f32x4 acc[16];
#pragma unroll
    for (int n = 0; n < 16; ++n) {
#pragma unroll
        for (int r = 0; r < 4; ++r) {
            int tlr = tl + r;
            acc[n][r] = bf2f(rp[tlr * 280 + (n * 16 + l15 - tlr + 15)]);
        }
    }
#pragma unroll
    for (int n = 0; n < 16; ++n) {
        s16x8 kf = *(const s16x8*)(qrow + (size_t)(n * 16 + l15) * 512 + 256 + h * 32 + quad * 8);
        acc[n] = __builtin_amdgcn_mfma_f32_16x16x32_bf16(afrag, kf, acc[n], 0, 0, 0);
    }

    // wave-local softmax (tree reductions)
    float invr[4];
#pragma unroll
    for (int r = 0; r < 4; ++r) {
        float tmp[16];
#pragma unroll
        for (int n = 0; n < 16; ++n) tmp[n] = acc[n][r];
#pragma unroll
        for (int st = 8; st; st >>= 1)
#pragma unroll
            for (int n = 0; n < 8; ++n)
                if (n < st) tmp[n] = fmaxf(tmp[n], tmp[n + st]);
        float m = tmp[0];
#pragma unroll
        for (int off = 1; off < 16; off <<= 1) m = fmaxf(m, __shfl_xor(m, off, 64));
        float sm[16];
#pragma unroll
        for (int n = 0; n < 16; ++n) {
            float e = __expf(acc[n][r] - m);
            acc[n][r] = e;
            sm[n] = e;
        }
#pragma unroll
        for (int st = 8; st; st >>= 1)
#pragma unroll
            for (int n = 0; n < 8; ++n)
                if (n < st) sm[n] += sm[n + st];
        float s = sm[0];
#pragma unroll
        for (int off = 1; off < 16; off <<= 1) s += __shfl_xor(s, off, 64);
        invr[r] = 1.f / s;
    }
    // write P over the (dead) R band — truncating stores, wave-local, no barrier
#pragma unroll
    for (int n = 0; n < 16; ++n) {
#pragma unroll
        for (int r = 0; r < 4; ++r)
            rp[(tl + r) * 280 + n * 16 + l15] = f2bf_rtz(acc[n][r] * invr[r]);
    }

    // ---- phase 3: O = P V^T (V direct from global; 2 d-tiles x 8 k-steps)
#pragma unroll
    for (int j = 0; j < 2; ++j) {
        f32x4 o = {0.f, 0.f, 0.f, 0.f};
#pragma unroll
        for (int ks = 0; ks < 8; ++ks) {
            s16x8 a  = *(const s16x8*)&rp[l15 * 280 + ks * 32 + quad * 8];
            s16x8 bv = *(const s16x8*)(vg + (size_t)(j * 16 + l15) * 256 + ks * 32 + quad * 8);
            o = __builtin_amdgcn_mfma_f32_16x16x32_bf16(a, bv, o, 0, 0, 0);
        }
        u16* ob = attn + ((size_t)b * 256 + t0w + tl) * 256 + h * 32 + j * 16 + l15;
        ob[0]   = f2bf(o[0]);
        ob[256] = f2bf(o[1]);
        ob[512] = f2bf(o[2]);
        ob[768] = f2bf(o[3]);
    }
}

// ---------------------------------------------------------------------------
// K5: out[n][o][t][v] = relu((y[b=(n,v)][o][t] + x[n][o][t][v]) * inv[o] + shift[o])
__global__ __launch_bounds__(256) void k_final(const u16* __restrict__ y,
                                               const float* __restrict__ x,
                                               const float* __restrict__ gamma,
                                               const float* __restrict__ beta,
                                               const float* __restrict__ mean,
                                               const float* __restrict__ var,
                                               float* __restrict__ out) {
    __shared__ float tile[1600];
    const int tid = threadIdx.x;
    const int t0 = blockIdx.x * 64;
    const int o  = blockIdx.y;
    const int n  = blockIdx.z;
    float inv = gamma[o] * rsqrtf(var[o] + 1e-5f);
    float sh  = beta[o] - mean[o] * inv;
    for (int p = tid; p < 1600; p += 256) {
        int v = p >> 6, j = p & 63;
        tile[j * VV + v] = bf2f(y[(((size_t)(n * VV + v)) * CC + o) * TT + t0 + j]);
    }
    __syncthreads();
    size_t gbase = (((size_t)(n * CC + o)) * TT + t0) * VV;
    for (int i = tid; i < 1600; i += 256) {
        float val = tile[i] + x[gbase + i];
        val = val * inv + sh;
        out[gbase + i] = fmaxf(val, 0.f);
    }
}

// ---------------------------------------------------------------------------
extern "C" void kernel_launch(void* const* d_in, const int* in_sizes, int n_in,
                              void* d_out, int out_size, void* d_ws, size_t ws_size,
                              hipStream_t stream) {
    const float* x        = (const float*)d_in[0];
    const float* qkv_w    = (const float*)d_in[1];
    const float* qkv_b    = (const float*)d_in[2];
    const float* key_rel  = (const float*)d_in[3];
    const float* attn_w   = (const float*)d_in[4];
    const float* attn_b   = (const float*)d_in[5];
    const float* bn_gamma = (const float*)d_in[6];
    const float* bn_beta  = (const float*)d_in[7];
    const float* bn_mean  = (const float*)d_in[8];
    const float* bn_var   = (const float*)d_in[9];
    float* out = (float*)d_out;

    // d_ws: 131,072,000 bytes
    char* ws = (char*)d_ws;
    u16* xT     = (u16*)ws;                    // 26,214,400
    u16* qk_all = (u16*)(ws + 26214400);       // 52,428,800  [b][t][512]
    u16* vb     = (u16*)(ws + 78643200);       // 26,214,400  [b][h][d][t]
    u16* attnT  = (u16*)(ws + 104857600);      // 26,214,400  [b][t][256]
    u16* y      = qk_all;  // qk_all dead after attention; reuse for y

    // d_out doubles as scratch for packed weights (dead before k_final overwrites)
    char* outc = (char*)d_out;
    u16* Wqk   = (u16*)outc;                // 262,144 B
    u16* Wv    = (u16*)(outc + 262144);     // 131,072 B
    u16* Wo    = (u16*)(outc + 393216);     // 131,072 B
    float* bqk = (float*)(outc + 524288);   //   2,048 B
    u16* krb   = (u16*)(outc + 526336);     //  32,768 B

    k_pack_all<<<1090, 256, 0, stream>>>(qkv_w, attn_w, qkv_b, key_rel, Wqk, Wv, Wo, bqk, krb);
    k_transpose_x<<<dim3(8, 8, 8), 256, 0, stream>>>(x, xT);
    k_gemm_qk<<<dim3(4, 2, 200), 256, 0, stream>>>(xT, Wqk, bqk, qk_all);
    k_gemm_av<<<dim3(2, 2, 200), 256, 0, stream>>>(Wv, qkv_b + 512, xT, vb);
    k_attention_mfma<<<dim3(1600, 4), 256, 0, stream>>>(qk_all, vb, krb, attnT);
    k_gemm_av<<<dim3(2, 2, 200), 256, 0, stream>>>(Wo, attn_b, attnT, y);
    k_final<<<dim3(4, 256, 8), 256, 0, stream>>>(y, x, bn_gamma, bn_beta, bn_mean, bn_var, out);
}

// Round 6
// 360.283 us; speedup vs baseline: 1.0025x; 1.0025x over previous
//
#include <hip/hip_runtime.h>

#define NB 8
#define CC 256
#define TT 256
#define VV 25

typedef unsigned int u32;
typedef unsigned short u16;
typedef __attribute__((ext_vector_type(8))) short s16x8;
typedef __attribute__((ext_vector_type(4))) float f32x4;

__device__ __forceinline__ float bf2f(u16 u) { return __uint_as_float((u32)u << 16); }
__device__ __forceinline__ u16 f2bf(float f) {
    u32 u = __float_as_uint(f);
    u += 0x7fffu + ((u >> 16) & 1u);
    return (u16)(u >> 16);
}
// truncating bf16 (1 ulp; compiles to lshr or d16_hi store)
__device__ __forceinline__ u16 f2bf_rtz(float f) { return (u16)(__float_as_uint(f) >> 16); }

__device__ __forceinline__ void gload_lds16(const void* g, void* l) {
    __builtin_amdgcn_global_load_lds(
        (const __attribute__((address_space(1))) u32*)g,
        (__attribute__((address_space(3))) u32*)l, 16, 0, 0);
}

// ---------------------------------------------------------------------------
// K1: x (N,C,T,V) f32 -> xT[b=(n*V+v)][t][c] bf16  (k-contiguous rows for MFMA A/B)
__global__ __launch_bounds__(256) void k_transpose_x(const float* __restrict__ x,
                                                     u16* __restrict__ xT) {
    __shared__ u16 L[25 * 32 * 34];
    const int tid = threadIdx.x;
    const int c0 = blockIdx.x * 32;
    const int t0 = blockIdx.y * 32;
    const int n  = blockIdx.z;
    for (int i = tid; i < 25600; i += 256) {
        int ci = i / 800;
        int rem = i - ci * 800;
        int t = rem / 25;
        int v = rem - t * 25;
        float f = x[(((size_t)(n * CC + c0 + ci)) * TT + t0) * VV + rem];
        L[(v * 32 + t) * 34 + ci] = f2bf(f);
    }
    __syncthreads();
    for (int i = tid; i < 12800; i += 256) {
        int row = i >> 4, cp = i & 15;
        int v = row >> 5, t = row & 31;
        u32 val = *(const u32*)&L[row * 34 + cp * 2];
        *(u32*)&xT[(((size_t)(n * VV + v)) * TT + t0 + t) * CC + c0 + cp * 2] = val;
    }
}

// ---------------------------------------------------------------------------
// K1b: pack weights (q rows pre-scaled), scaled q bias, krel (512 rows, last zeroed)
__global__ __launch_bounds__(256) void k_pack_all(const float* __restrict__ qkv_w,
                                                  const float* __restrict__ attn_w,
                                                  const float* __restrict__ qkv_b,
                                                  const float* __restrict__ key_rel,
                                                  u16* __restrict__ Wqk,
                                                  u16* __restrict__ Wv,
                                                  u16* __restrict__ Wo,
                                                  float* __restrict__ bqk,
                                                  u16* __restrict__ krb) {
    const float s = 0.17677669529663687f;   // 1/sqrt(32)
    int g = blockIdx.x * 256 + threadIdx.x;
    if (g < 131072) {
        Wqk[g] = f2bf(qkv_w[g] * (g < 65536 ? s : 1.f));
    } else if (g < 196608) {
        Wv[g - 131072] = f2bf(qkv_w[g]);             // qkv_w rows 512..767
    } else if (g < 262144) {
        Wo[g - 196608] = f2bf(attn_w[g - 196608]);
    } else if (g < 262656) {
        int i = g - 262144;
        bqk[i] = qkv_b[i] * (i < 256 ? s : 1.f);
    } else if (g < 279040) {
        int i = g - 262656;
        krb[i] = (i < 511 * 32) ? f2bf(key_rel[i]) : (u16)0;
    }
}

// ---------------------------------------------------------------------------
// m97-style mainloop: 128x128 tile, BK=32, async global->LDS, 4 waves x (4x4) 16x16 tiles.
__device__ __forceinline__ void gemm_mainloop(const u16* __restrict__ Arow,
                                              const u16* __restrict__ Brow,
                                              u16* At, u16* Bt,
                                              int wave, int lane, f32x4 acc[4][4]) {
    const int srow = lane >> 2, scol = (lane & 3) * 8;
    const int quad = lane >> 4, l15 = lane & 15;
    for (int k0 = 0; k0 < 256; k0 += 32) {
#pragma unroll
        for (int it = 0; it < 2; ++it) {
            int ch = it * 4 + wave;
            gload_lds16(Arow + (size_t)(ch * 16 + srow) * 256 + k0 + scol, At + ch * 512 + lane * 8);
            gload_lds16(Brow + (size_t)(ch * 16 + srow) * 256 + k0 + scol, Bt + ch * 512 + lane * 8);
        }
        __syncthreads();
        s16x8 af[4], bfr[4];
#pragma unroll
        for (int i = 0; i < 4; ++i)
            af[i] = *(const s16x8*)&At[((wave & 1) * 64 + i * 16 + l15) * 32 + quad * 8];
#pragma unroll
        for (int j = 0; j < 4; ++j)
            bfr[j] = *(const s16x8*)&Bt[((wave >> 1) * 64 + j * 16 + l15) * 32 + quad * 8];
#pragma unroll
        for (int i = 0; i < 4; ++i)
#pragma unroll
            for (int j = 0; j < 4; ++j)
                acc[i][j] = __builtin_amdgcn_mfma_f32_16x16x32_bf16(af[i], bfr[j], acc[i][j], 0, 0, 0);
        __syncthreads();
    }
}

// ---------------------------------------------------------------------------
// K2a: C[t][o] = xT . Wqk^T + bqk  -> qk_all[b][t][512]  (cols 0..255 q, 256..511 k)
__global__ __launch_bounds__(256) void k_gemm_qk(const u16* __restrict__ xT,
                                                 const u16* __restrict__ Wqk,
                                                 const float* __restrict__ bqk,
                                                 u16* __restrict__ qk_all) {
    __shared__ __align__(16) u16 At[128 * 32];
    __shared__ __align__(16) u16 Bt[128 * 32];
    const int tid = threadIdx.x, wave = tid >> 6, lane = tid & 63;
    const int quad = lane >> 4, l15 = lane & 15;
    const int n0 = blockIdx.x * 128;     // o
    const int m0 = blockIdx.y * 128;     // t
    const int b  = blockIdx.z;
    const u16* Arow = xT + (size_t)b * 65536 + (size_t)m0 * 256;
    const u16* Brow = Wqk + (size_t)n0 * 256;
    f32x4 acc[4][4];
#pragma unroll
    for (int i = 0; i < 4; ++i)
#pragma unroll
        for (int j = 0; j < 4; ++j) acc[i][j] = (f32x4){0.f, 0.f, 0.f, 0.f};
    gemm_mainloop(Arow, Brow, At, Bt, wave, lane, acc);

    u16* ob = qk_all + (size_t)b * 131072;
    const int nb = n0 + (wave >> 1) * 64 + l15;
    float bj[4];
#pragma unroll
    for (int j = 0; j < 4; ++j) bj[j] = bqk[nb + j * 16];
#pragma unroll
    for (int i = 0; i < 4; ++i) {
        int t_i = m0 + (wave & 1) * 64 + i * 16 + quad * 4;
#pragma unroll
        for (int r = 0; r < 4; ++r) {
            u16* orow = ob + (size_t)(t_i + r) * 512 + nb;
#pragma unroll
            for (int j = 0; j < 4; ++j)
                orow[j * 16] = f2bf(acc[i][j][r] + bj[j]);
        }
    }
}

// ---------------------------------------------------------------------------
// K2b (used twice): C[o][t] = W . Bsrc^T + bias -> Out[b][o][t]
__global__ __launch_bounds__(256) void k_gemm_av(const u16* __restrict__ Wb,
                                                 const float* __restrict__ bias,
                                                 const u16* __restrict__ Bsrc,
                                                 u16* __restrict__ Out) {
    __shared__ __align__(16) u16 At[128 * 32];
    __shared__ __align__(16) u16 Bt[128 * 32];
    const int tid = threadIdx.x, wave = tid >> 6, lane = tid & 63;
    const int quad = lane >> 4, l15 = lane & 15;
    const int n0 = blockIdx.x * 128;     // t
    const int m0 = blockIdx.y * 128;     // o
    const int b  = blockIdx.z;
    const u16* Arow = Wb + (size_t)m0 * 256;
    const u16* Brow = Bsrc + (size_t)b * 65536 + (size_t)n0 * 256;
    f32x4 acc[4][4];
#pragma unroll
    for (int i = 0; i < 4; ++i)
#pragma unroll
        for (int j = 0; j < 4; ++j) acc[i][j] = (f32x4){0.f, 0.f, 0.f, 0.f};
    gemm_mainloop(Arow, Brow, At, Bt, wave, lane, acc);

    u16* ob = Out + (size_t)b * 65536;
    const int nb = n0 + (wave >> 1) * 64 + l15;
#pragma unroll
    for (int i = 0; i < 4; ++i) {
        int o_i = m0 + (wave & 1) * 64 + i * 16 + quad * 4;
#pragma unroll
        for (int r = 0; r < 4; ++r) {
            float bv = bias[o_i + r];
            u16* orow = ob + (size_t)(o_i + r) * 256 + nb;
#pragma unroll
            for (int j = 0; j < 4; ++j)
                orow[j * 16] = f2bf(acc[i][j][r] + bv);
        }
    }
}

// ---------------------------------------------------------------------------
// K3: wave-autonomous MFMA attention, register-batched.
// __launch_bounds__(256,3): VGPR cap ~168 so batched loads stay in flight
// (at 64 VGPRs the compiler serialized every load->use: R5 post-mortem).
// XCD swizzle: all 8 heads of one b (sharing Q rows / qk_all lines) on one XCD.
__global__ __launch_bounds__(256, 3) void k_attention_mfma(const u16* __restrict__ qk,
                                                           const u16* __restrict__ vb,
                                                           const u16* __restrict__ krb,
                                                           u16* __restrict__ attn) {
    __shared__ __align__(16) u16 RP[4][16 * 280];

    const int tid = threadIdx.x;
    const int L = blockIdx.x;
    const int b = (L & 7) * 25 + ((L >> 3) % 25);
    const int h = L / 200;
    const int bh = b * 8 + h;
    const int wave = tid >> 6, lane = tid & 63;
    const int quad = lane >> 4, l15 = lane & 15;
    const int t0w = blockIdx.y * 64 + wave * 16;    // this wave's first t-row
    const int tl = quad * 4;                        // C-layout row base (t-local)

    u16* rp = &RP[wave][0];
    const u16* qrow = qk + (size_t)b * 131072;             // [t][512]
    const u16* vg   = vb + (size_t)bh * 8192;              // [d][t]
    const u16* krg  = krb + (size_t)(240 - t0w) * 32;      // m = col + 240 - t0w

    // A fragment: Q rows t0w..t0w+15
    s16x8 afrag = *(const s16x8*)(qrow + (size_t)(t0w + l15) * 512 + h * 32 + quad * 8);

    // ---- phase 1: batch all 17 KR-fragment loads, then MFMA + store R band
    s16x8 krf[17];
#pragma unroll
    for (int j = 0; j < 17; ++j)
        krf[j] = *(const s16x8*)(krg + (size_t)(j * 16 + l15) * 32 + quad * 8);
#pragma unroll
    for (int j = 0; j < 17; ++j) {
        f32x4 c = {0.f, 0.f, 0.f, 0.f};
        c = __builtin_amdgcn_mfma_f32_16x16x32_bf16(afrag, krf[j], c, 0, 0, 0);
        int col = j * 16 + l15;
        rp[(tl + 0) * 280 + col] = f2bf_rtz(c[0]);
        rp[(tl + 1) * 280 + col] = f2bf_rtz(c[1]);
        rp[(tl + 2) * 280 + col] = f2bf_rtz(c[2]);
        rp[(tl + 3) * 280 + col] = f2bf_rtz(c[3]);
    }

    // ---- phase 2: batch 16 K-frag loads (VMEM) + 64 gather reads (LDS), then MFMAs
    s16x8 kf[16];
#pragma unroll
    for (int n = 0; n < 16; ++n)
        kf[n] = *(const s16x8*)(qrow + (size_t)(n * 16 + l15) * 512 + 256 + h * 32 + quad * 8);
    f32x4 acc[16];
#pragma unroll
    for (int n = 0; n < 16; ++n) {
#pragma unroll
        for (int r = 0; r < 4; ++r) {
            int tlr = tl + r;
            acc[n][r] = bf2f(rp[tlr * 280 + (n * 16 + l15 - tlr + 15)]);
        }
    }
#pragma unroll
    for (int n = 0; n < 16; ++n)
        acc[n] = __builtin_amdgcn_mfma_f32_16x16x32_bf16(afrag, kf[n], acc[n], 0, 0, 0);

    // wave-local softmax (tree reductions)
    float invr[4];
#pragma unroll
    for (int r = 0; r < 4; ++r) {
        float tmp[16];
#pragma unroll
        for (int n = 0; n < 16; ++n) tmp[n] = acc[n][r];
#pragma unroll
        for (int st = 8; st; st >>= 1)
#pragma unroll
            for (int n = 0; n < 8; ++n)
                if (n < st) tmp[n] = fmaxf(tmp[n], tmp[n + st]);
        float m = tmp[0];
#pragma unroll
        for (int off = 1; off < 16; off <<= 1) m = fmaxf(m, __shfl_xor(m, off, 64));
        float sm[16];
#pragma unroll
        for (int n = 0; n < 16; ++n) {
            float e = __expf(acc[n][r] - m);
            acc[n][r] = e;
            sm[n] = e;
        }
#pragma unroll
        for (int st = 8; st; st >>= 1)
#pragma unroll
            for (int n = 0; n < 8; ++n)
                if (n < st) sm[n] += sm[n + st];
        float s = sm[0];
#pragma unroll
        for (int off = 1; off < 16; off <<= 1) s += __shfl_xor(s, off, 64);
        invr[r] = 1.f / s;
    }
    // write P over the (dead) R band — truncating stores, wave-local, no barrier
#pragma unroll
    for (int n = 0; n < 16; ++n) {
#pragma unroll
        for (int r = 0; r < 4; ++r)
            rp[(tl + r) * 280 + n * 16 + l15] = f2bf_rtz(acc[n][r] * invr[r]);
    }

    // ---- phase 3: O = P V^T, batched frags, 2 independent MFMA chains per d-tile
#pragma unroll
    for (int j = 0; j < 2; ++j) {
        s16x8 vf[8], pa[8];
#pragma unroll
        for (int ks = 0; ks < 8; ++ks)
            vf[ks] = *(const s16x8*)(vg + (size_t)(j * 16 + l15) * 256 + ks * 32 + quad * 8);
#pragma unroll
        for (int ks = 0; ks < 8; ++ks)
            pa[ks] = *(const s16x8*)&rp[l15 * 280 + ks * 32 + quad * 8];
        f32x4 o0 = {0.f, 0.f, 0.f, 0.f}, o1 = {0.f, 0.f, 0.f, 0.f};
#pragma unroll
        for (int ks = 0; ks < 8; ks += 2) {
            o0 = __builtin_amdgcn_mfma_f32_16x16x32_bf16(pa[ks],     vf[ks],     o0, 0, 0, 0);
            o1 = __builtin_amdgcn_mfma_f32_16x16x32_bf16(pa[ks + 1], vf[ks + 1], o1, 0, 0, 0);
        }
        u16* ob = attn + ((size_t)b * 256 + t0w + tl) * 256 + h * 32 + j * 16 + l15;
        ob[0]   = f2bf(o0[0] + o1[0]);
        ob[256] = f2bf(o0[1] + o1[1]);
        ob[512] = f2bf(o0[2] + o1[2]);
        ob[768] = f2bf(o0[3] + o1[3]);
    }
}

// ---------------------------------------------------------------------------
// K5: out[n][o][t][v] = relu((y[b=(n,v)][o][t] + x[n][o][t][v]) * inv[o] + shift[o])
__global__ __launch_bounds__(256) void k_final(const u16* __restrict__ y,
                                               const float* __restrict__ x,
                                               const float* __restrict__ gamma,
                                               const float* __restrict__ beta,
                                               const float* __restrict__ mean,
                                               const float* __restrict__ var,
                                               float* __restrict__ out) {
    __shared__ float tile[1600];
    const int tid = threadIdx.x;
    const int t0 = blockIdx.x * 64;
    const int o  = blockIdx.y;
    const int n  = blockIdx.z;
    float inv = gamma[o] * rsqrtf(var[o] + 1e-5f);
    float sh  = beta[o] - mean[o] * inv;
    for (int p = tid; p < 1600; p += 256) {
        int v = p >> 6, j = p & 63;
        tile[j * VV + v] = bf2f(y[(((size_t)(n * VV + v)) * CC + o) * TT + t0 + j]);
    }
    __syncthreads();
    size_t gbase = (((size_t)(n * CC + o)) * TT + t0) * VV;
    for (int i = tid; i < 1600; i += 256) {
        float val = tile[i] + x[gbase + i];
        val = val * inv + sh;
        out[gbase + i] = fmaxf(val, 0.f);
    }
}

// ---------------------------------------------------------------------------
extern "C" void kernel_launch(void* const* d_in, const int* in_sizes, int n_in,
                              void* d_out, int out_size, void* d_ws, size_t ws_size,
                              hipStream_t stream) {
    const float* x        = (const float*)d_in[0];
    const float* qkv_w    = (const float*)d_in[1];
    const float* qkv_b    = (const float*)d_in[2];
    const float* key_rel  = (const float*)d_in[3];
    const float* attn_w   = (const float*)d_in[4];
    const float* attn_b   = (const float*)d_in[5];
    const float* bn_gamma = (const float*)d_in[6];
    const float* bn_beta  = (const float*)d_in[7];
    const float* bn_mean  = (const float*)d_in[8];
    const float* bn_var   = (const float*)d_in[9];
    float* out = (float*)d_out;

    // d_ws: 131,072,000 bytes
    char* ws = (char*)d_ws;
    u16* xT     = (u16*)ws;                    // 26,214,400
    u16* qk_all = (u16*)(ws + 26214400);       // 52,428,800  [b][t][512]
    u16* vb     = (u16*)(ws + 78643200);       // 26,214,400  [b][h][d][t]
    u16* attnT  = (u16*)(ws + 104857600);      // 26,214,400  [b][t][256]
    u16* y      = qk_all;  // qk_all dead after attention; reuse for y

    // d_out doubles as scratch for packed weights (dead before k_final overwrites)
    char* outc = (char*)d_out;
    u16* Wqk   = (u16*)outc;                // 262,144 B
    u16* Wv    = (u16*)(outc + 262144);     // 131,072 B
    u16* Wo    = (u16*)(outc + 393216);     // 131,072 B
    float* bqk = (float*)(outc + 524288);   //   2,048 B
    u16* krb   = (u16*)(outc + 526336);     //  32,768 B

    k_pack_all<<<1090, 256, 0, stream>>>(qkv_w, attn_w, qkv_b, key_rel, Wqk, Wv, Wo, bqk, krb);
    k_transpose_x<<<dim3(8, 8, 8), 256, 0, stream>>>(x, xT);
    k_gemm_qk<<<dim3(4, 2, 200), 256, 0, stream>>>(xT, Wqk, bqk, qk_all);
    k_gemm_av<<<dim3(2, 2, 200), 256, 0, stream>>>(Wv, qkv_b + 512, xT, vb);
    k_attention_mfma<<<dim3(1600, 4), 256, 0, stream>>>(qk_all, vb, krb, attnT);
    k_gemm_av<<<dim3(2, 2, 200), 256, 0, stream>>>(Wo, attn_b, attnT, y);
    k_final<<<dim3(4, 256, 8), 256, 0, stream>>>(y, x, bn_gamma, bn_beta, bn_mean, bn_var, out);
}

// Round 7
// 352.811 us; speedup vs baseline: 1.0238x; 1.0212x over previous
//
#include <hip/hip_runtime.h>

#define NB 8
#define CC 256
#define TT 256
#define VV 25

typedef unsigned int u32;
typedef unsigned short u16;
typedef __attribute__((ext_vector_type(8))) short s16x8;
typedef __attribute__((ext_vector_type(4))) float f32x4;

__device__ __forceinline__ float bf2f(u16 u) { return __uint_as_float((u32)u << 16); }
__device__ __forceinline__ u16 f2bf(float f) {
    u32 u = __float_as_uint(f);
    u += 0x7fffu + ((u >> 16) & 1u);
    return (u16)(u >> 16);
}
// truncating bf16 (1 ulp; compiles to lshr or d16_hi store)
__device__ __forceinline__ u16 f2bf_rtz(float f) { return (u16)(__float_as_uint(f) >> 16); }

__device__ __forceinline__ void gload_lds16(const void* g, void* l) {
    __builtin_amdgcn_global_load_lds(
        (const __attribute__((address_space(1))) u32*)g,
        (__attribute__((address_space(3))) u32*)l, 16, 0, 0);
}

// ---------------------------------------------------------------------------
// K1: x (N,C,T,V) f32 -> xT[b=(n*V+v)][t][c] bf16  (k-contiguous rows for MFMA A/B)
__global__ __launch_bounds__(256) void k_transpose_x(const float* __restrict__ x,
                                                     u16* __restrict__ xT) {
    __shared__ u16 L[25 * 32 * 34];
    const int tid = threadIdx.x;
    const int c0 = blockIdx.x * 32;
    const int t0 = blockIdx.y * 32;
    const int n  = blockIdx.z;
    for (int i = tid; i < 25600; i += 256) {
        int ci = i / 800;
        int rem = i - ci * 800;
        int t = rem / 25;
        int v = rem - t * 25;
        float f = x[(((size_t)(n * CC + c0 + ci)) * TT + t0) * VV + rem];
        L[(v * 32 + t) * 34 + ci] = f2bf(f);
    }
    __syncthreads();
    for (int i = tid; i < 12800; i += 256) {
        int row = i >> 4, cp = i & 15;
        int v = row >> 5, t = row & 31;
        u32 val = *(const u32*)&L[row * 34 + cp * 2];
        *(u32*)&xT[(((size_t)(n * VV + v)) * TT + t0 + t) * CC + c0 + cp * 2] = val;
    }
}

// ---------------------------------------------------------------------------
// K1b: pack weights (q rows pre-scaled), scaled q bias, krel, BN inv/shift
__global__ __launch_bounds__(256) void k_pack_all(const float* __restrict__ qkv_w,
                                                  const float* __restrict__ attn_w,
                                                  const float* __restrict__ qkv_b,
                                                  const float* __restrict__ key_rel,
                                                  const float* __restrict__ bn_gamma,
                                                  const float* __restrict__ bn_beta,
                                                  const float* __restrict__ bn_mean,
                                                  const float* __restrict__ bn_var,
                                                  u16* __restrict__ Wqk,
                                                  u16* __restrict__ Wv,
                                                  u16* __restrict__ Wo,
                                                  float* __restrict__ bqk,
                                                  u16* __restrict__ krb,
                                                  float* __restrict__ bnis) {
    const float s = 0.17677669529663687f;   // 1/sqrt(32)
    int g = blockIdx.x * 256 + threadIdx.x;
    if (g < 131072) {
        Wqk[g] = f2bf(qkv_w[g] * (g < 65536 ? s : 1.f));
    } else if (g < 196608) {
        Wv[g - 131072] = f2bf(qkv_w[g]);             // qkv_w rows 512..767
    } else if (g < 262144) {
        Wo[g - 196608] = f2bf(attn_w[g - 196608]);
    } else if (g < 262656) {
        int i = g - 262144;
        bqk[i] = qkv_b[i] * (i < 256 ? s : 1.f);
    } else if (g < 279040) {
        int i = g - 262656;
        krb[i] = (i < 511 * 32) ? f2bf(key_rel[i]) : (u16)0;
    } else if (g < 279552) {
        int i = g - 279040;
        if (i < 256) {
            bnis[i] = bn_gamma[i] * rsqrtf(bn_var[i] + 1e-5f);          // inv
        } else {
            int o = i - 256;
            float iv = bn_gamma[o] * rsqrtf(bn_var[o] + 1e-5f);
            bnis[i] = bn_beta[o] - bn_mean[o] * iv;                     // shift
        }
    }
}

// ---------------------------------------------------------------------------
// m97-style mainloop: 128x128 tile, BK=32, async global->LDS, 4 waves x (4x4) 16x16 tiles.
__device__ __forceinline__ void gemm_mainloop(const u16* __restrict__ Arow,
                                              const u16* __restrict__ Brow,
                                              u16* At, u16* Bt,
                                              int wave, int lane, f32x4 acc[4][4]) {
    const int srow = lane >> 2, scol = (lane & 3) * 8;
    const int quad = lane >> 4, l15 = lane & 15;
    for (int k0 = 0; k0 < 256; k0 += 32) {
#pragma unroll
        for (int it = 0; it < 2; ++it) {
            int ch = it * 4 + wave;
            gload_lds16(Arow + (size_t)(ch * 16 + srow) * 256 + k0 + scol, At + ch * 512 + lane * 8);
            gload_lds16(Brow + (size_t)(ch * 16 + srow) * 256 + k0 + scol, Bt + ch * 512 + lane * 8);
        }
        __syncthreads();
        s16x8 af[4], bfr[4];
#pragma unroll
        for (int i = 0; i < 4; ++i)
            af[i] = *(const s16x8*)&At[((wave & 1) * 64 + i * 16 + l15) * 32 + quad * 8];
#pragma unroll
        for (int j = 0; j < 4; ++j)
            bfr[j] = *(const s16x8*)&Bt[((wave >> 1) * 64 + j * 16 + l15) * 32 + quad * 8];
#pragma unroll
        for (int i = 0; i < 4; ++i)
#pragma unroll
            for (int j = 0; j < 4; ++j)
                acc[i][j] = __builtin_amdgcn_mfma_f32_16x16x32_bf16(af[i], bfr[j], acc[i][j], 0, 0, 0);
        __syncthreads();
    }
}

// ---------------------------------------------------------------------------
// K2: merged QKV GEMM per b.
//   bx<4: C[t][o]=xT·Wqk^T + bqk -> qk_all[b][t][512]
//   bx>=4: C[d][t]=Wv·xT^T + qkv_b[512+] -> vb[b][h][d][t]
__global__ __launch_bounds__(256) void k_gemm_qkv(const u16* __restrict__ xT,
                                                  const u16* __restrict__ Wqk,
                                                  const u16* __restrict__ Wv,
                                                  const float* __restrict__ bqk,
                                                  const float* __restrict__ qkv_b,
                                                  u16* __restrict__ qk_all,
                                                  u16* __restrict__ vb) {
    __shared__ __align__(16) u16 At[128 * 32];
    __shared__ __align__(16) u16 Bt[128 * 32];
    const int tid = threadIdx.x, wave = tid >> 6, lane = tid & 63;
    const int quad = lane >> 4, l15 = lane & 15;
    const int bx = blockIdx.x;
    const int b  = blockIdx.z;
    const bool isv = (bx >= 4);
    const int n0 = (isv ? blockIdx.y : bx) * 128;
    const int m0 = (isv ? (bx - 4) : (int)blockIdx.y) * 128;
    const u16* xb = xT + (size_t)b * 65536;
    const u16* Arow = isv ? (Wv + (size_t)m0 * 256) : (xb + (size_t)m0 * 256);
    const u16* Brow = isv ? (xb + (size_t)n0 * 256) : (Wqk + (size_t)n0 * 256);
    f32x4 acc[4][4];
#pragma unroll
    for (int i = 0; i < 4; ++i)
#pragma unroll
        for (int j = 0; j < 4; ++j) acc[i][j] = (f32x4){0.f, 0.f, 0.f, 0.f};
    gemm_mainloop(Arow, Brow, At, Bt, wave, lane, acc);

    const int nb = n0 + (wave >> 1) * 64 + l15;
    if (!isv) {
        u16* ob = qk_all + (size_t)b * 131072;
        float bj[4];
#pragma unroll
        for (int j = 0; j < 4; ++j) bj[j] = bqk[nb + j * 16];
#pragma unroll
        for (int i = 0; i < 4; ++i) {
            int t_i = m0 + (wave & 1) * 64 + i * 16 + quad * 4;
#pragma unroll
            for (int r = 0; r < 4; ++r) {
                u16* orow = ob + (size_t)(t_i + r) * 512 + nb;
#pragma unroll
                for (int j = 0; j < 4; ++j)
                    orow[j * 16] = f2bf(acc[i][j][r] + bj[j]);
            }
        }
    } else {
        u16* ob = vb + (size_t)b * 65536;
#pragma unroll
        for (int i = 0; i < 4; ++i) {
            int o_i = m0 + (wave & 1) * 64 + i * 16 + quad * 4;
#pragma unroll
            for (int r = 0; r < 4; ++r) {
                float bv = qkv_b[512 + o_i + r];
                u16* orow = ob + (size_t)(o_i + r) * 256 + nb;
#pragma unroll
                for (int j = 0; j < 4; ++j)
                    orow[j * 16] = f2bf(acc[i][j][r] + bv);
            }
        }
    }
}

// ---------------------------------------------------------------------------
// K3: wave-autonomous MFMA attention (round-6 body). Output: attnF[n][t][v][c].
__global__ __launch_bounds__(256, 3) void k_attention_mfma(const u16* __restrict__ qk,
                                                           const u16* __restrict__ vb,
                                                           const u16* __restrict__ krb,
                                                           u16* __restrict__ attnF) {
    __shared__ __align__(16) u16 RP[4][16 * 280];

    const int tid = threadIdx.x;
    const int L = blockIdx.x;
    const int n = L & 7;
    const int v = (L >> 3) % 25;
    const int b = n * 25 + v;
    const int h = L / 200;
    const int bh = b * 8 + h;
    const int wave = tid >> 6, lane = tid & 63;
    const int quad = lane >> 4, l15 = lane & 15;
    const int t0w = blockIdx.y * 64 + wave * 16;    // this wave's first t-row
    const int tl = quad * 4;                        // C-layout row base (t-local)

    u16* rp = &RP[wave][0];
    const u16* qrow = qk + (size_t)b * 131072;             // [t][512]
    const u16* vg   = vb + (size_t)bh * 8192;              // [d][t]
    const u16* krg  = krb + (size_t)(240 - t0w) * 32;      // m = col + 240 - t0w

    // A fragment: Q rows t0w..t0w+15
    s16x8 afrag = *(const s16x8*)(qrow + (size_t)(t0w + l15) * 512 + h * 32 + quad * 8);

    // ---- phase 1: batch all 17 KR-fragment loads, then MFMA + store R band
    s16x8 krf[17];
#pragma unroll
    for (int j = 0; j < 17; ++j)
        krf[j] = *(const s16x8*)(krg + (size_t)(j * 16 + l15) * 32 + quad * 8);
#pragma unroll
    for (int j = 0; j < 17; ++j) {
        f32x4 c = {0.f, 0.f, 0.f, 0.f};
        c = __builtin_amdgcn_mfma_f32_16x16x32_bf16(afrag, krf[j], c, 0, 0, 0);
        int col = j * 16 + l15;
        rp[(tl + 0) * 280 + col] = f2bf_rtz(c[0]);
        rp[(tl + 1) * 280 + col] = f2bf_rtz(c[1]);
        rp[(tl + 2) * 280 + col] = f2bf_rtz(c[2]);
        rp[(tl + 3) * 280 + col] = f2bf_rtz(c[3]);
    }

    // ---- phase 2: batch 16 K-frag loads (VMEM) + 64 gather reads (LDS), then MFMAs
    s16x8 kf[16];
#pragma unroll
    for (int nn = 0; nn < 16; ++nn)
        kf[nn] = *(const s16x8*)(qrow + (size_t)(nn * 16 + l15) * 512 + 256 + h * 32 + quad * 8);
    f32x4 acc[16];
#pragma unroll
    for (int nn = 0; nn < 16; ++nn) {
#pragma unroll
        for (int r = 0; r < 4; ++r) {
            int tlr = tl + r;
            acc[nn][r] = bf2f(rp[tlr * 280 + (nn * 16 + l15 - tlr + 15)]);
        }
    }
#pragma unroll
    for (int nn = 0; nn < 16; ++nn)
        acc[nn] = __builtin_amdgcn_mfma_f32_16x16x32_bf16(afrag, kf[nn], acc[nn], 0, 0, 0);

    // wave-local softmax (tree reductions)
    float invr[4];
#pragma unroll
    for (int r = 0; r < 4; ++r) {
        float tmp[16];
#pragma unroll
        for (int nn = 0; nn < 16; ++nn) tmp[nn] = acc[nn][r];
#pragma unroll
        for (int st = 8; st; st >>= 1)
#pragma unroll
            for (int nn = 0; nn < 8; ++nn)
                if (nn < st) tmp[nn] = fmaxf(tmp[nn], tmp[nn + st]);
        float m = tmp[0];
#pragma unroll
        for (int off = 1; off < 16; off <<= 1) m = fmaxf(m, __shfl_xor(m, off, 64));
        float sm[16];
#pragma unroll
        for (int nn = 0; nn < 16; ++nn) {
            float e = __expf(acc[nn][r] - m);
            acc[nn][r] = e;
            sm[nn] = e;
        }
#pragma unroll
        for (int st = 8; st; st >>= 1)
#pragma unroll
            for (int nn = 0; nn < 8; ++nn)
                if (nn < st) sm[nn] += sm[nn + st];
        float s = sm[0];
#pragma unroll
        for (int off = 1; off < 16; off <<= 1) s += __shfl_xor(s, off, 64);
        invr[r] = 1.f / s;
    }
    // write P over the (dead) R band — truncating stores, wave-local, no barrier
#pragma unroll
    for (int nn = 0; nn < 16; ++nn) {
#pragma unroll
        for (int r = 0; r < 4; ++r)
            rp[(tl + r) * 280 + nn * 16 + l15] = f2bf_rtz(acc[nn][r] * invr[r]);
    }

    // ---- phase 3: O = P V^T, batched frags, 2 independent MFMA chains per d-tile
#pragma unroll
    for (int j = 0; j < 2; ++j) {
        s16x8 vf[8], pa[8];
#pragma unroll
        for (int ks = 0; ks < 8; ++ks)
            vf[ks] = *(const s16x8*)(vg + (size_t)(j * 16 + l15) * 256 + ks * 32 + quad * 8);
#pragma unroll
        for (int ks = 0; ks < 8; ++ks)
            pa[ks] = *(const s16x8*)&rp[l15 * 280 + ks * 32 + quad * 8];
        f32x4 o0 = {0.f, 0.f, 0.f, 0.f}, o1 = {0.f, 0.f, 0.f, 0.f};
#pragma unroll
        for (int ks = 0; ks < 8; ks += 2) {
            o0 = __builtin_amdgcn_mfma_f32_16x16x32_bf16(pa[ks],     vf[ks],     o0, 0, 0, 0);
            o1 = __builtin_amdgcn_mfma_f32_16x16x32_bf16(pa[ks + 1], vf[ks + 1], o1, 0, 0, 0);
        }
        // attnF[n][t][v][c]: rows t stride 25*256
        u16* ob = attnF + (((size_t)(n * 256 + t0w + tl)) * 25 + v) * 256 + h * 32 + j * 16 + l15;
        ob[0]        = f2bf(o0[0] + o1[0]);
        ob[6400]     = f2bf(o0[1] + o1[1]);
        ob[12800]    = f2bf(o0[2] + o1[2]);
        ob[19200]    = f2bf(o0[3] + o1[3]);
    }
}

// ---------------------------------------------------------------------------
// K4: fused out-projection + residual + BN + ReLU, per n:
//   C[o][tv] = Wo · attnF[n]^T;  out[n][o][tv] = relu((C+ab+x)*inv + sh)
__global__ __launch_bounds__(256) void k_gemm_out(const u16* __restrict__ Wo,
                                                  const float* __restrict__ attn_b,
                                                  const u16* __restrict__ attnF,
                                                  const float* __restrict__ x,
                                                  const float* __restrict__ bnis,
                                                  float* __restrict__ out) {
    __shared__ __align__(16) u16 At[128 * 32];
    __shared__ __align__(16) u16 Bt[128 * 32];
    const int tid = threadIdx.x, wave = tid >> 6, lane = tid & 63;
    const int quad = lane >> 4, l15 = lane & 15;
    const int n0 = blockIdx.x * 128;     // tv
    const int m0 = blockIdx.y * 128;     // o
    const int n  = blockIdx.z;
    const u16* Arow = Wo + (size_t)m0 * 256;
    const u16* Brow = attnF + (size_t)n * 6400 * 256 + (size_t)n0 * 256;
    f32x4 acc[4][4];
#pragma unroll
    for (int i = 0; i < 4; ++i)
#pragma unroll
        for (int j = 0; j < 4; ++j) acc[i][j] = (f32x4){0.f, 0.f, 0.f, 0.f};
    gemm_mainloop(Arow, Brow, At, Bt, wave, lane, acc);

    const int nb = n0 + (wave >> 1) * 64 + l15;
#pragma unroll
    for (int i = 0; i < 4; ++i) {
        int o_i = m0 + (wave & 1) * 64 + i * 16 + quad * 4;
#pragma unroll
        for (int r = 0; r < 4; ++r) {
            int o = o_i + r;
            float ab = attn_b[o];
            float iv = bnis[o];
            float sh = bnis[256 + o];
            const float* xrow = x + ((size_t)(n * 256 + o)) * 6400;
            float* orow = out + ((size_t)(n * 256 + o)) * 6400;
#pragma unroll
            for (int j = 0; j < 4; ++j) {
                int col = nb + j * 16;
                float val = (acc[i][j][r] + ab + xrow[col]) * iv + sh;
                orow[col] = fmaxf(val, 0.f);
            }
        }
    }
}

// ---------------------------------------------------------------------------
extern "C" void kernel_launch(void* const* d_in, const int* in_sizes, int n_in,
                              void* d_out, int out_size, void* d_ws, size_t ws_size,
                              hipStream_t stream) {
    const float* x        = (const float*)d_in[0];
    const float* qkv_w    = (const float*)d_in[1];
    const float* qkv_b    = (const float*)d_in[2];
    const float* key_rel  = (const float*)d_in[3];
    const float* attn_w   = (const float*)d_in[4];
    const float* attn_b   = (const float*)d_in[5];
    const float* bn_gamma = (const float*)d_in[6];
    const float* bn_beta  = (const float*)d_in[7];
    const float* bn_mean  = (const float*)d_in[8];
    const float* bn_var   = (const float*)d_in[9];
    float* out = (float*)d_out;

    // d_ws layout (105.4 MB used):
    //   [0]           xT (dead after qkv) -> reused as attnF   26,214,400
    //   [26,214,400]  qk_all [b][t][512]                       52,428,800
    //   [78,643,200]  vb [b][h][d][t]                          26,214,400
    //   [104,857,600] weight/param scratch                        561,152
    char* ws = (char*)d_ws;
    u16* xT     = (u16*)ws;
    u16* attnF  = (u16*)ws;                    // reuses xT slot
    u16* qk_all = (u16*)(ws + 26214400);
    u16* vb     = (u16*)(ws + 78643200);
    char* wsc   = ws + 104857600;
    u16* Wqk    = (u16*)wsc;                   // 262,144 B
    u16* Wv     = (u16*)(wsc + 262144);        // 131,072 B
    u16* Wo     = (u16*)(wsc + 393216);        // 131,072 B
    float* bqk  = (float*)(wsc + 524288);      //   2,048 B
    u16* krb    = (u16*)(wsc + 526336);        //  32,768 B
    float* bnis = (float*)(wsc + 559104);      //   2,048 B

    k_pack_all<<<1092, 256, 0, stream>>>(qkv_w, attn_w, qkv_b, key_rel,
                                         bn_gamma, bn_beta, bn_mean, bn_var,
                                         Wqk, Wv, Wo, bqk, krb, bnis);
    k_transpose_x<<<dim3(8, 8, 8), 256, 0, stream>>>(x, xT);
    k_gemm_qkv<<<dim3(6, 2, 200), 256, 0, stream>>>(xT, Wqk, Wv, bqk, qkv_b, qk_all, vb);
    k_attention_mfma<<<dim3(1600, 4), 256, 0, stream>>>(qk_all, vb, krb, attnF);
    k_gemm_out<<<dim3(50, 2, 8), 256, 0, stream>>>(Wo, attn_b, attnF, x, bnis, out);
}